// Round 17
// baseline (309.097 us; speedup 1.0000x reference)
//
#include <hip/hip_runtime.h>
#include <hip/hip_fp16.h>

typedef _Float16 v8h __attribute__((ext_vector_type(8)));
typedef float    v4f __attribute__((ext_vector_type(4)));

__device__ __forceinline__ float lrelu(float x){ return x >= 0.f ? x : 0.2f*x; }

#define SB 256  // scan blocks

// ---------------- zero degree counters ----------------
__global__ __launch_bounds__(256) void k_zero(int* __restrict__ p, int n)
{
  int i = blockIdx.x*256 + threadIdx.x;
  if (i < n) p[i] = 0;
}

// ---------------- count in-degree per destination ----------------
__global__ __launch_bounds__(256) void k_count(const int* __restrict__ ei,
                                               int E, int N, int* __restrict__ deg)
{
  const int e = blockIdx.x*256 + threadIdx.x;
  if (e >= E + N) return;
  const int d = (e < E) ? ei[E + e] : (e - E);
  atomicAdd(&deg[d], 1);
}

// ---------------- parallel scan phase 1 ----------------
__global__ __launch_bounds__(256) void k_scan1(const int* __restrict__ deg,
                                               int* __restrict__ bsum, int N)
{
  __shared__ int sh[256];
  const int chunk = (N + SB - 1) / SB;
  const int lo = blockIdx.x * chunk;
  const int hi = min(lo + chunk, N);
  int s = 0;
  for (int i = lo + threadIdx.x; i < hi; i += 256) s += deg[i];
  sh[threadIdx.x] = s;
  __syncthreads();
  #pragma unroll
  for (int off = 128; off; off >>= 1){
    if (threadIdx.x < off) sh[threadIdx.x] += sh[threadIdx.x + off];
    __syncthreads();
  }
  if (threadIdx.x == 0) bsum[blockIdx.x] = sh[0];
}

// ---------------- parallel scan phase 2 ----------------
__global__ __launch_bounds__(256) void k_scan2(int* __restrict__ bsum)
{
  __shared__ int sh[256];
  const int v = bsum[threadIdx.x];
  sh[threadIdx.x] = v;
  __syncthreads();
  for (int off = 1; off < 256; off <<= 1){
    int t = 0;
    if (threadIdx.x >= off) t = sh[threadIdx.x - off];
    __syncthreads();
    sh[threadIdx.x] += t;
    __syncthreads();
  }
  bsum[threadIdx.x] = sh[threadIdx.x] - v;  // exclusive
}

// ---------------- parallel scan phase 3 ----------------
__global__ __launch_bounds__(256) void k_scan3(const int* __restrict__ deg,
                                               const int* __restrict__ bsum,
                                               int* __restrict__ rowptr,
                                               int* __restrict__ cursor, int N)
{
  __shared__ int sh[256];
  const int chunk = (N + SB - 1) / SB;
  const int lo = blockIdx.x * chunk;
  const int hi = min(lo + chunk, N);
  int base = bsum[blockIdx.x];
  for (int start = lo; start < hi; start += 256){
    const int i = start + threadIdx.x;
    const int v = (i < hi) ? deg[i] : 0;
    sh[threadIdx.x] = v;
    __syncthreads();
    for (int off = 1; off < 256; off <<= 1){
      int t = 0;
      if (threadIdx.x >= off) t = sh[threadIdx.x - off];
      __syncthreads();
      sh[threadIdx.x] += t;
      __syncthreads();
    }
    if (i < hi){
      const int excl = base + sh[threadIdx.x] - v;
      rowptr[i] = excl;
      cursor[i] = excl;
    }
    base += sh[255];
    __syncthreads();
  }
  if (blockIdx.x == SB-1 && threadIdx.x == 0) rowptr[N] = base;
}

// ---------------- fill CSR src lists ----------------
__global__ __launch_bounds__(256) void k_fill(const int* __restrict__ ei,
                                              int E, int N, int* __restrict__ cursor,
                                              int* __restrict__ csr)
{
  const int e = blockIdx.x*256 + threadIdx.x;
  if (e >= E + N) return;
  int s, d;
  if (e < E){ s = ei[e]; d = ei[E + e]; } else { s = d = e - E; }
  const int pos = atomicAdd(&cursor[d], 1);
  csr[pos] = s;
}

// ---------------- combined weight prep: pack W1, pack W2, Ps/Pd -------------
__global__ __launch_bounds__(256) void k_wprep(
    const float* __restrict__ W1, const float* __restrict__ W2,
    const float* __restrict__ as1, const float* __restrict__ ad1,
    _Float16* __restrict__ Wp1, _Float16* __restrict__ Wp2,
    float* __restrict__ Ps, float* __restrict__ Pd)
{
  const int b = blockIdx.x, t = threadIdx.x;
  if (b < 128){
    const int idx = b*256 + t;                 // 32768 total
    const int e = idx & 7, lane = (idx >> 3) & 63;
    const int ks = (idx >> 9) & 3, tct = idx >> 11;
    Wp1[idx] = (_Float16)W1[(size_t)(ks*32 + (lane>>4)*8 + e)*256 + tct*16 + (lane&15)];
  } else if (b < 384){
    const int idx = (b-128)*256 + t;           // 65536 total
    const int e = idx & 7, lane = (idx >> 3) & 63;
    const int ks = (idx >> 9) & 7, tct = idx >> 12;
    Wp2[idx] = (_Float16)W2[(size_t)(ks*32 + (lane>>4)*8 + e)*256 + tct*16 + (lane&15)];
  } else {
    for (int idx = t; idx < 512; idx += 256){
      const int k = idx >> 2, h = idx & 3;
      float ss = 0.f, dd = 0.f;
      for (int c = 0; c < 64; c++){
        const float wv = W1[k*256 + h*64 + c];
        ss += wv * as1[h*64 + c];
        dd += wv * ad1[h*64 + c];
      }
      Ps[k*4 + h] = ss;
      Pd[k*4 + h] = dd;
    }
  }
}

// ---------------- layer-1 logits + fused x->fp16 conversion -----------------
__global__ __launch_bounds__(256) void k_att1(
    const float* __restrict__ x, const float* __restrict__ Ps,
    const float* __restrict__ Pd, float* __restrict__ asrc,
    float* __restrict__ adst, __half* __restrict__ xh, int N)
{
  __shared__ float PsL[512], PdL[512];
  __shared__ float red[4][64][8];
  const int t = threadIdx.x;
  PsL[t] = Ps[t]; PsL[t+256] = Ps[t+256];
  PdL[t] = Pd[t]; PdL[t+256] = Pd[t+256];
  __syncthreads();
  const int r = t & 63, g = t >> 6;
  const int row = blockIdx.x*64 + r;
  const int rg = min(row, N-1);
  const float* xr = x + (size_t)rg*128;
  float4 pa = make_float4(0.f,0.f,0.f,0.f);
  float4 pb = make_float4(0.f,0.f,0.f,0.f);
  for (int kk = g*32; kk < g*32 + 32; kk++){
    const float xv = xr[kk];
    const float4 s4 = *(const float4*)(PsL + kk*4);
    const float4 d4 = *(const float4*)(PdL + kk*4);
    pa.x += xv*s4.x; pa.y += xv*s4.y; pa.z += xv*s4.z; pa.w += xv*s4.w;
    pb.x += xv*d4.x; pb.y += xv*d4.y; pb.z += xv*d4.z; pb.w += xv*d4.w;
  }
  *(float4*)(&red[g][r][0]) = pa;
  *(float4*)(&red[g][r][4]) = pb;
  // fused coalesced fp16 conversion of this block's 64 rows (single-writer)
  {
    const long base = (long)blockIdx.x * 8192;
    const long total = (long)N * 128;
    for (int i = t; i < 4096; i += 256){
      const long i2 = base + 2*(long)i;
      if (i2 + 1 < total){
        const float2 v = *(const float2*)(x + i2);
        *(__half2*)(xh + i2) = __floats2half2_rn(v.x, v.y);
      }
    }
  }
  __syncthreads();
  if (t < 64 && blockIdx.x*64 + t < N){
    float4 sa = make_float4(0.f,0.f,0.f,0.f);
    float4 sb = make_float4(0.f,0.f,0.f,0.f);
    #pragma unroll
    for (int gg = 0; gg < 4; gg++){
      const float4 qa = *(const float4*)(&red[gg][t][0]);
      const float4 qb = *(const float4*)(&red[gg][t][4]);
      sa.x += qa.x; sa.y += qa.y; sa.z += qa.z; sa.w += qa.w;
      sb.x += qb.x; sb.y += qb.y; sb.z += qb.z; sb.w += qb.w;
    }
    *(float4*)(asrc + (size_t)(blockIdx.x*64 + t)*4) = sa;
    *(float4*)(adst + (size_t)(blockIdx.x*64 + t)*4) = sb;
  }
}

// ---------------- layer-1 aggregate: dedup'd weights + packed aggX store ----
__global__ __launch_bounds__(256) void k_agg_x(
    const int* __restrict__ rowptr, const int* __restrict__ csr,
    const float* __restrict__ asrc, const float* __restrict__ adst,
    const __half* __restrict__ xh,
    __half* __restrict__ aggXp, int N)
{
  __shared__ float wbuf[4][16][4];
  __shared__ int   sbuf[4][16];
  const int wid = threadIdx.x >> 6;
  const int n = blockIdx.x*4 + wid;
  const int l = threadIdx.x & 63;
  if (n >= N) return;
  const int start = rowptr[n];
  const int deg = rowptr[n+1] - start;
  const float4 ad = *(const float4*)(adst + (size_t)n*4);
  const int jj = l & 15, hh = l >> 4;
  const float adh = hh==0?ad.x : hh==1?ad.y : hh==2?ad.z : ad.w;

  float a0x=0.f,a0y=0.f, a1x=0.f,a1y=0.f, a2x=0.f,a2y=0.f, a3x=0.f,a3y=0.f;
  float4 ds = make_float4(0.f,0.f,0.f,0.f);
  for (int c = 0; c < deg; c += 16){
    const int cnt = min(16, deg - c);
    const int sE = csr[start + c + min(jj, cnt-1)];
    const float q = asrc[(size_t)sE*4 + hh];
    const float wE = (jj < cnt) ? __expf(lrelu(q + adh)) : 0.f;
    wbuf[wid][jj][hh] = wE;
    if (hh == 0) sbuf[wid][jj] = sE;
    asm volatile("s_waitcnt lgkmcnt(0)" ::: "memory");  // pin LDS write->read order
    __builtin_amdgcn_wave_barrier();
    int j = 0;
    for (; j + 4 <= cnt; j += 4){
      const int t0 = sbuf[wid][j+0], t1 = sbuf[wid][j+1];
      const int t2 = sbuf[wid][j+2], t3 = sbuf[wid][j+3];
      const float4 wA = *(const float4*)(&wbuf[wid][j+0][0]);
      const float4 wB = *(const float4*)(&wbuf[wid][j+1][0]);
      const float4 wC = *(const float4*)(&wbuf[wid][j+2][0]);
      const float4 wD = *(const float4*)(&wbuf[wid][j+3][0]);
      const float2 f0 = __half22float2(*(const __half2*)(xh + (size_t)t0*128 + 2*l));
      const float2 f1 = __half22float2(*(const __half2*)(xh + (size_t)t1*128 + 2*l));
      const float2 f2 = __half22float2(*(const __half2*)(xh + (size_t)t2*128 + 2*l));
      const float2 f3 = __half22float2(*(const __half2*)(xh + (size_t)t3*128 + 2*l));
      a0x += wA.x*f0.x + wB.x*f1.x + wC.x*f2.x + wD.x*f3.x;
      a0y += wA.x*f0.y + wB.x*f1.y + wC.x*f2.y + wD.x*f3.y;
      a1x += wA.y*f0.x + wB.y*f1.x + wC.y*f2.x + wD.y*f3.x;
      a1y += wA.y*f0.y + wB.y*f1.y + wC.y*f2.y + wD.y*f3.y;
      a2x += wA.z*f0.x + wB.z*f1.x + wC.z*f2.x + wD.z*f3.x;
      a2y += wA.z*f0.y + wB.z*f1.y + wC.z*f2.y + wD.z*f3.y;
      a3x += wA.w*f0.x + wB.w*f1.x + wC.w*f2.x + wD.w*f3.x;
      a3y += wA.w*f0.y + wB.w*f1.y + wC.w*f2.y + wD.w*f3.y;
      ds.x += wA.x+wB.x+wC.x+wD.x;
      ds.y += wA.y+wB.y+wC.y+wD.y;
      ds.z += wA.z+wB.z+wC.z+wD.z;
      ds.w += wA.w+wB.w+wC.w+wD.w;
    }
    for (; j < cnt; j++){
      const int t0 = sbuf[wid][j];
      const float4 wA = *(const float4*)(&wbuf[wid][j][0]);
      const float2 f0 = __half22float2(*(const __half2*)(xh + (size_t)t0*128 + 2*l));
      a0x += wA.x*f0.x; a0y += wA.x*f0.y;
      a1x += wA.y*f0.x; a1y += wA.y*f0.y;
      a2x += wA.z*f0.x; a2y += wA.z*f0.y;
      a3x += wA.w*f0.x; a3y += wA.w*f0.y;
      ds.x += wA.x; ds.y += wA.y; ds.z += wA.z; ds.w += wA.w;
    }
    asm volatile("s_waitcnt lgkmcnt(0)" ::: "memory");
    __builtin_amdgcn_wave_barrier();
  }
  const float i0 = 1.f/ds.x, i1 = 1.f/ds.y, i2 = 1.f/ds.z, i3 = 1.f/ds.w;
  const int nb = n >> 4, r = n & 15;
  const int ksA = l >> 4;
  const int laneA = r + (((2*l) >> 3) & 3) * 16;
  const int e0 = (2*l) & 7;
  const size_t base = (((size_t)nb*4)*4 + ksA)*64*8 + (size_t)laneA*8 + e0;
  *(__half2*)(aggXp + base +    0) = __floats2half2_rn(a0x*i0, a0y*i0);
  *(__half2*)(aggXp + base + 2048) = __floats2half2_rn(a1x*i1, a1y*i1);
  *(__half2*)(aggXp + base + 4096) = __floats2half2_rn(a2x*i2, a2y*i2);
  *(__half2*)(aggXp + base + 6144) = __floats2half2_rn(a3x*i3, a3y*i3);
}

// ---------------- FUSED MFMA, 8 waves, all operand loads coalesced ----------
__global__ __launch_bounds__(512) void k_gemm_fused(
    const _Float16* __restrict__ aggXp, // [nb][4][4][64][8]
    const _Float16* __restrict__ Wp1,   // [16][4][64][8]
    const float* __restrict__ b1,
    const _Float16* __restrict__ Wp2,   // [16][8][64][8]
    const float* __restrict__ att_s, const float* __restrict__ att_d,
    __half* __restrict__ h2t,           // [N,64,4] halves
    float* __restrict__ asrc, float* __restrict__ adst, int N)
{
  __shared__ _Float16 h1[64][264];
  const int wv = threadIdx.x >> 6, l = threadIdx.x & 63;
  const int wr = wv & 3, wc = wv >> 2;
  const int lr = l & 15, lk = l >> 4;
  const int row0 = blockIdx.x*64 + wr*16;
  const int nb = blockIdx.x*4 + wr;

  {
    v4f acc[8] = {};
    for (int ks = 0; ks < 4; ks++){
      const v8h a0 = *(const v8h*)(aggXp + ((((size_t)nb*4 + 2*wc  )*4 + ks)*64 + l)*8);
      const v8h a1 = *(const v8h*)(aggXp + ((((size_t)nb*4 + 2*wc+1)*4 + ks)*64 + l)*8);
      #pragma unroll
      for (int ct = 0; ct < 8; ct++){
        const int tct = wc*8 + ct;
        const v8h b = *(const v8h*)(Wp1 + (((size_t)tct*4 + ks)*64 + l)*8);
        acc[ct] = __builtin_amdgcn_mfma_f32_16x16x32_f16(ct < 4 ? a0 : a1, b, acc[ct], 0,0,0);
      }
    }
    #pragma unroll
    for (int ct = 0; ct < 8; ct++){
      const int col = wc*128 + ct*16 + lr;
      const float bv = b1[col];
      #pragma unroll
      for (int j = 0; j < 4; j++)
        h1[wr*16 + lk*4 + j][col] = (_Float16)fmaxf(acc[ct][j] + bv, 0.f);
    }
  }
  __syncthreads();

  v4f acc[8] = {};
  for (int ks = 0; ks < 8; ks++){
    const v8h a = *(const v8h*)(&h1[wr*16 + lr][ks*32 + lk*8]);
    #pragma unroll
    for (int ct = 0; ct < 8; ct++){
      const int tct = wc*8 + ct;
      const v8h b = *(const v8h*)(Wp2 + (((size_t)tct*8 + ks)*64 + l)*8);
      acc[ct] = __builtin_amdgcn_mfma_f32_16x16x32_f16(a, b, acc[ct], 0,0,0);
    }
  }
  float AS[8], AD[8];
  #pragma unroll
  for (int ct = 0; ct < 8; ct++){
    const int h = 2*wc + (ct >> 2), idx = (ct & 3)*16 + lr;
    AS[ct] = att_s[h*64 + idx];
    AD[ct] = att_d[h*64 + idx];
  }
  #pragma unroll
  for (int j = 0; j < 4; j++){
    const int row = row0 + lk*4 + j;
    const bool ok = row < N;
    float vs0=0.f, vd0=0.f, vs1=0.f, vd1=0.f;
    #pragma unroll
    for (int ct = 0; ct < 8; ct++){
      const float v = acc[ct][j];
      if (ct < 4){ vs0 += v*AS[ct]; vd0 += v*AD[ct]; }
      else       { vs1 += v*AS[ct]; vd1 += v*AD[ct]; }
    }
    if (ok){
      #pragma unroll
      for (int ctm = 0; ctm < 4; ctm++){
        const int ch = ctm*16 + lr;
        *(__half2*)(h2t + (size_t)row*256 + ch*4 + 2*wc) =
            __floats2half2_rn(acc[ctm][j], acc[ctm+4][j]);
      }
    }
    #pragma unroll
    for (int off = 1; off < 16; off <<= 1){
      vs0 += __shfl_xor(vs0, off, 16);
      vd0 += __shfl_xor(vd0, off, 16);
      vs1 += __shfl_xor(vs1, off, 16);
      vd1 += __shfl_xor(vd1, off, 16);
    }
    if (lr == 0 && ok){
      asrc[(size_t)row*4 + 2*wc    ] = vs0;
      adst[(size_t)row*4 + 2*wc    ] = vd0;
      asrc[(size_t)row*4 + 2*wc + 1] = vs1;
      adst[(size_t)row*4 + 2*wc + 1] = vd1;
    }
  }
}

// ---------------- layer-2 aggregation (R15-proven form) ----------------
__global__ __launch_bounds__(256) void k_node_agg2(
    const int* __restrict__ rowptr, const int* __restrict__ csr,
    const float* __restrict__ asrc, const float* __restrict__ adst,
    const __half* __restrict__ h2t, const float* __restrict__ bias,
    float* __restrict__ outp, int N)
{
  __shared__ float wbuf[4][16][4];
  __shared__ int   sbuf[4][16];
  const int wid = threadIdx.x >> 6;
  const int n = blockIdx.x*4 + wid;
  const int l = threadIdx.x & 63;              // output channel
  if (n >= N) return;
  const int start = rowptr[n];
  const int deg = rowptr[n+1] - start;
  const float4 ad = *(const float4*)(adst + (size_t)n*4);
  const int jj = l & 15, hh = l >> 4;
  const float adh = hh==0?ad.x : hh==1?ad.y : hh==2?ad.z : ad.w;

  float a0=0.f, a1=0.f, a2=0.f, a3=0.f;
  float4 ds = make_float4(0.f,0.f,0.f,0.f);
  for (int c = 0; c < deg; c += 16){
    const int cnt = min(16, deg - c);
    const int sE = csr[start + c + min(jj, cnt-1)];
    const float q = asrc[(size_t)sE*4 + hh];
    const float wE = (jj < cnt) ? __expf(lrelu(q + adh)) : 0.f;
    wbuf[wid][jj][hh] = wE;
    if (hh == 0) sbuf[wid][jj] = sE;
    asm volatile("s_waitcnt lgkmcnt(0)" ::: "memory");  // pin LDS write->read order
    __builtin_amdgcn_wave_barrier();
    int j = 0;
    for (; j + 4 <= cnt; j += 4){
      const int t0 = sbuf[wid][j+0], t1 = sbuf[wid][j+1];
      const int t2 = sbuf[wid][j+2], t3 = sbuf[wid][j+3];
      const float4 wA = *(const float4*)(&wbuf[wid][j+0][0]);
      const float4 wB = *(const float4*)(&wbuf[wid][j+1][0]);
      const float4 wC = *(const float4*)(&wbuf[wid][j+2][0]);
      const float4 wD = *(const float4*)(&wbuf[wid][j+3][0]);
      const uint2 u0 = *(const uint2*)(h2t + (size_t)t0*256 + l*4);
      const uint2 u1 = *(const uint2*)(h2t + (size_t)t1*256 + l*4);
      const uint2 u2 = *(const uint2*)(h2t + (size_t)t2*256 + l*4);
      const uint2 u3 = *(const uint2*)(h2t + (size_t)t3*256 + l*4);
      const float2 g0 = __half22float2(*reinterpret_cast<const __half2*>(&u0.x));
      const float2 g1 = __half22float2(*reinterpret_cast<const __half2*>(&u0.y));
      const float2 h0 = __half22float2(*reinterpret_cast<const __half2*>(&u1.x));
      const float2 h1 = __half22float2(*reinterpret_cast<const __half2*>(&u1.y));
      const float2 i0 = __half22float2(*reinterpret_cast<const __half2*>(&u2.x));
      const float2 i1 = __half22float2(*reinterpret_cast<const __half2*>(&u2.y));
      const float2 k0 = __half22float2(*reinterpret_cast<const __half2*>(&u3.x));
      const float2 k1 = __half22float2(*reinterpret_cast<const __half2*>(&u3.y));
      a0 += wA.x*g0.x + wB.x*h0.x + wC.x*i0.x + wD.x*k0.x;
      a1 += wA.y*g0.y + wB.y*h0.y + wC.y*i0.y + wD.y*k0.y;
      a2 += wA.z*g1.x + wB.z*h1.x + wC.z*i1.x + wD.z*k1.x;
      a3 += wA.w*g1.y + wB.w*h1.y + wC.w*i1.y + wD.w*k1.y;
      ds.x += wA.x+wB.x+wC.x+wD.x;
      ds.y += wA.y+wB.y+wC.y+wD.y;
      ds.z += wA.z+wB.z+wC.z+wD.z;
      ds.w += wA.w+wB.w+wC.w+wD.w;
    }
    for (; j < cnt; j++){
      const int t0 = sbuf[wid][j];
      const float4 wA = *(const float4*)(&wbuf[wid][j][0]);
      const uint2 u = *(const uint2*)(h2t + (size_t)t0*256 + l*4);
      const float2 f01 = __half22float2(*reinterpret_cast<const __half2*>(&u.x));
      const float2 f23 = __half22float2(*reinterpret_cast<const __half2*>(&u.y));
      a0 += wA.x*f01.x; a1 += wA.y*f01.y; a2 += wA.z*f23.x; a3 += wA.w*f23.y;
      ds.x += wA.x; ds.y += wA.y; ds.z += wA.z; ds.w += wA.w;
    }
    asm volatile("s_waitcnt lgkmcnt(0)" ::: "memory");
    __builtin_amdgcn_wave_barrier();
  }
  const float val = 0.25f*(a0/ds.x + a1/ds.y + a2/ds.z + a3/ds.w) + bias[l];
  outp[(size_t)n*64 + l] = fmaxf(val, 0.f);
}

// ---------------- FF head: agg2 -> relu(@ff1) -> @ff2 (R15-proven) ----------
__global__ __launch_bounds__(256) void k_ff(
    const float* __restrict__ agg2,
    const float* __restrict__ w1, const float* __restrict__ b1,
    const float* __restrict__ w2, const float* __restrict__ b2f,
    float* __restrict__ out, int N)
{
  __shared__ float W1s[64*32];
  __shared__ float B1s[32];
  __shared__ float W2s[64];
  __shared__ float B2s[2];
  const int t = threadIdx.x;
  for (int i=t; i<64*32; i+=256) W1s[i] = w1[i];
  if (t < 32) B1s[t] = b1[t];
  if (t < 64) W2s[t] = w2[t];
  if (t < 2)  B2s[t] = b2f[t];
  __syncthreads();

  const int n = blockIdx.x*256 + t;
  if (n >= N) return;

  float t1[32];
  #pragma unroll
  for (int j=0;j<32;j++) t1[j] = B1s[j];
  #pragma unroll
  for (int c=0;c<64;c++){
    const float fc = agg2[(long)n*64 + c];
    #pragma unroll
    for (int j=0;j<32;j++) t1[j] += fc * W1s[c*32 + j];
  }
  float o0 = B2s[0], o1 = B2s[1];
  #pragma unroll
  for (int j=0;j<32;j++){
    const float v = t1[j] > 0.f ? t1[j] : 0.f;
    o0 += v * W2s[j*2 + 0];
    o1 += v * W2s[j*2 + 1];
  }
  out[(long)n*2 + 0] = o0;
  out[(long)n*2 + 1] = o1;
}

extern "C" void kernel_launch(void* const* d_in, const int* in_sizes, int n_in,
                              void* d_out, int out_size, void* d_ws, size_t ws_size,
                              hipStream_t stream)
{
  const float* x      = (const float*)d_in[0];
  const int*   ei     = (const int*)  d_in[1];
  const float* W1     = (const float*)d_in[3];
  const float* att_s1 = (const float*)d_in[4];
  const float* att_d1 = (const float*)d_in[5];
  const float* b1     = (const float*)d_in[6];
  const float* W2     = (const float*)d_in[7];
  const float* att_s2 = (const float*)d_in[8];
  const float* att_d2 = (const float*)d_in[9];
  const float* b2     = (const float*)d_in[10];
  const float* ff1w   = (const float*)d_in[11];
  const float* ff1b   = (const float*)d_in[12];
  const float* ff2w   = (const float*)d_in[13];
  const float* ff2b   = (const float*)d_in[14];
  float* out = (float*)d_out;

  const int N = in_sizes[0] / 128;
  const int E = in_sizes[1] / 2;
  const int tot = E + N;
  const int g64 = (N + 63) / 64;
  const size_t NP = (size_t)g64 * 64;

  // ---- workspace ----
  char* p = (char*)d_ws;
  __half* aggXp = (__half*)p;                        // [NP,512] halves packed
  p += NP*1024;
  float* agg2 = (float*)p;  p += (size_t)N*64*4;     // [N,64]
  __half* xh  = (__half*)p; p += (size_t)N*128*2;    // [N,128]
  __half* h2t = (__half*)p; p += (size_t)N*256*2;    // [N,256]
  float* asrc = (float*)p;  p += (size_t)N*4*4;
  float* adst = (float*)p;  p += (size_t)N*4*4;
  float* Ps   = (float*)p;  p += 512*4;
  float* Pd   = (float*)p;  p += 512*4;
  _Float16* Wp1 = (_Float16*)p; p += 32768*2;        // [16][4][64][8]
  _Float16* Wp2 = (_Float16*)p; p += 65536*2;        // [16][8][64][8]
  int* deg    = (int*)p;    p += (size_t)N*4;
  int* rowptr = (int*)p;    p += (size_t)(N+1)*4;
  int* cursor = (int*)p;    p += (size_t)N*4;
  int* bsum   = (int*)p;    p += SB*4;
  int* csr    = (int*)p;    p += (size_t)tot*4;

  const int gE  = (tot + 255) / 256;
  const int gN4 = (N + 3) / 4;

  // ---- CSR build ----
  k_zero <<<(N+255)/256,256,0,stream>>>(deg, N);
  k_count<<<gE,256,0,stream>>>(ei, E, N, deg);
  k_scan1<<<SB,256,0,stream>>>(deg, bsum, N);
  k_scan2<<<1,256,0,stream>>>(bsum);
  k_scan3<<<SB,256,0,stream>>>(deg, bsum, rowptr, cursor, N);
  k_fill <<<gE,256,0,stream>>>(ei, E, N, cursor, csr);

  // ---- combined weight prep ----
  k_wprep<<<385,256,0,stream>>>(W1, W2, att_s1, att_d1, Wp1, Wp2, Ps, Pd);

  // ---- layer 1 (att1 also emits fp16 x) ----
  k_att1<<<g64,256,0,stream>>>(x, Ps, Pd, asrc, adst, xh, N);
  k_agg_x<<<gN4,256,0,stream>>>(rowptr, csr, asrc, adst, xh, (__half*)aggXp, N);

  // ---- fused gemm1+gemm2 ----
  k_gemm_fused<<<g64,512,0,stream>>>((const _Float16*)aggXp, Wp1, b1, Wp2,
                                     att_s2, att_d2, h2t, asrc, adst, N);

  // ---- layer-2 aggregation + FF head ----
  k_node_agg2<<<gN4,256,0,stream>>>(rowptr, csr, asrc, adst, h2t, b2, agg2, N);
  k_ff<<<(N+255)/256,256,0,stream>>>(agg2, ff1w, ff1b, ff2w, ff2b, out, N);
}